// Round 11
// baseline (188.260 us; speedup 1.0000x reference)
//
#include <hip/hip_runtime.h>
#include <hip/hip_fp16.h>
#include <math.h>

#define BATCH 16384
#define MAXF 32
#define NFEAT 768
#define FT_OUT 1024
#define CHUNK 64                      // columns per chunk: 128-B LDS row = all 32 banks
#define NCHUNK (FT_OUT / CHUNK)       // 16 chunks
#define GROUPS 16                     // stripes per chunk -> 256 blocks = 1/CU
#define CH_HALVES (NFEAT * CHUNK)     // 49152 halves = 96 KiB (dynamic LDS)
#define LDS_BYTES (CH_HALVES * 2)

// compile-time component select for unrolled loops (f is a constant after unroll)
#define GET4(a, f) (((f) & 3) == 0 ? (a)[(f) >> 2].x : \
                    ((f) & 3) == 1 ? (a)[(f) >> 2].y : \
                    ((f) & 3) == 2 ? (a)[(f) >> 2].z : (a)[(f) >> 2].w)

typedef unsigned int uint_t;

// Main: stage fp32 chunk -> f16 LDS (128-B rows: a sample's 8 lanes x b128
// sweep all 32 banks exactly once -> conflict-free by construction), stream
// samples, plain-store per-chunk partials. 256 threads (R7 lesson: 512-thread
// codegen spills the GET4 preload arrays to scratch; 256-thread is proven at
// VGPR=80). NO __threadfence (R8->R9: device fence = L2 wb-inv = 2.7x slowdown).
__global__ __launch_bounds__(256, 1) void nnboard_main(
    const float* __restrict__ values,
    const int*   __restrict__ stm_idx,
    const int*   __restrict__ nstm_idx,
    const float* __restrict__ ft_w,
    const float* __restrict__ ft_b,
    const float* __restrict__ out_w,
    float*       __restrict__ partials)   // [NCHUNK][BATCH]
{
    extern __shared__ __half s_tab[];     // [NFEAT][CHUNK], row = 128 B

    const int tid = threadIdx.x;
    const int c = blockIdx.x & (NCHUNK - 1);  // chunk: cols [64c, 64c+64)
    const int g = blockIdx.x >> 4;            // stripe 0..15
    const __half2 zero2 = __float2half2_rn(0.f);

    // ---- stage chunk c from fp32 ft_w: 8 lanes/row (8 cols each), 24 sweeps
    {
        const int lane8 = tid & 7;
        const int rbase = tid >> 3;           // 32 rows per sweep
        #pragma unroll
        for (int k = 0; k < NFEAT / 32; ++k) {
            const int r = k * 32 + rbase;
            const float* src = ft_w + (size_t)r * FT_OUT + c * CHUNK + lane8 * 8;
            const float4 f0 = *(const float4*)(src);
            const float4 f1 = *(const float4*)(src + 4);
            __half2 h0 = __floats2half2_rn(f0.x, f0.y);
            __half2 h1 = __floats2half2_rn(f0.z, f0.w);
            __half2 h2 = __floats2half2_rn(f1.x, f1.y);
            __half2 h3 = __floats2half2_rn(f1.z, f1.w);
            uint4 u;
            u.x = *reinterpret_cast<uint_t*>(&h0);
            u.y = *reinterpret_cast<uint_t*>(&h1);
            u.z = *reinterpret_cast<uint_t*>(&h2);
            u.w = *reinterpret_cast<uint_t*>(&h3);
            *(uint4*)(s_tab + r * CHUNK + lane8 * 8) = u;  // 8 lanes = full 128-B row
        }
    }
    __syncthreads();

    const int grp = tid >> 3;             // 0..31 : sample slot per iteration
    const int jj  = tid & 7;              // lane within sample (owns 8 cols)
    const int col0 = c * CHUNK + jj * 8;
    const __half* my_tab = s_tab + jj * 8;   // + row*CHUNK per gathered row

    const float4 bia0 = *(const float4*)(ft_b + col0);
    const float4 bia1 = *(const float4*)(ft_b + col0 + 4);
    const float4 ws0  = *(const float4*)(out_w + col0);
    const float4 ws1  = *(const float4*)(out_w + col0 + 4);
    const float4 wn0  = *(const float4*)(out_w + FT_OUT + col0);
    const float4 wn1  = *(const float4*)(out_w + FT_OUT + col0 + 4);

    for (int it = g; it < BATCH / 32; it += GROUPS) {
        const int b = it * 32 + grp;

        const int4*   sp = (const int4*)(stm_idx + b * MAXF);
        const int4*   np = (const int4*)(nstm_idx + b * MAXF);
        const float4* vp = (const float4*)(values + b * MAXF);
        int4 si[8], ni[8];
        float4 vv[8];
        #pragma unroll
        for (int k = 0; k < 8; ++k) { si[k] = sp[k]; ni[k] = np[k]; vv[k] = vp[k]; }

        __half2 accs[4] = {zero2, zero2, zero2, zero2};
        __half2 accn[4] = {zero2, zero2, zero2, zero2};

        #pragma unroll
        for (int f = 0; f < MAXF; ++f) {
            const int is = GET4(si, f);
            const int in = GET4(ni, f);
            const __half2 v2 = __float2half2_rn(GET4(vv, f));
            const uint4 qs = *(const uint4*)(my_tab + is * CHUNK);
            const uint4 qn = *(const uint4*)(my_tab + in * CHUNK);
            accs[0] = __hfma2(*(const __half2*)&qs.x, v2, accs[0]);
            accs[1] = __hfma2(*(const __half2*)&qs.y, v2, accs[1]);
            accs[2] = __hfma2(*(const __half2*)&qs.z, v2, accs[2]);
            accs[3] = __hfma2(*(const __half2*)&qs.w, v2, accs[3]);
            accn[0] = __hfma2(*(const __half2*)&qn.x, v2, accn[0]);
            accn[1] = __hfma2(*(const __half2*)&qn.y, v2, accn[1]);
            accn[2] = __hfma2(*(const __half2*)&qn.z, v2, accn[2]);
            accn[3] = __hfma2(*(const __half2*)&qn.w, v2, accn[3]);
        }

        float p = 0.f;
        {
            const float2 f0 = __half22float2(accs[0]);
            const float2 f1 = __half22float2(accs[1]);
            const float2 f2 = __half22float2(accs[2]);
            const float2 f3 = __half22float2(accs[3]);
            const float2 g0 = __half22float2(accn[0]);
            const float2 g1 = __half22float2(accn[1]);
            const float2 g2 = __half22float2(accn[2]);
            const float2 g3 = __half22float2(accn[3]);
            auto clip = [](float x) { return fminf(fmaxf(x, 0.f), 1.f); };
            p = fmaf(clip(f0.x + bia0.x), ws0.x, p);
            p = fmaf(clip(f0.y + bia0.y), ws0.y, p);
            p = fmaf(clip(f1.x + bia0.z), ws0.z, p);
            p = fmaf(clip(f1.y + bia0.w), ws0.w, p);
            p = fmaf(clip(f2.x + bia1.x), ws1.x, p);
            p = fmaf(clip(f2.y + bia1.y), ws1.y, p);
            p = fmaf(clip(f3.x + bia1.z), ws1.z, p);
            p = fmaf(clip(f3.y + bia1.w), ws1.w, p);
            p = fmaf(clip(g0.x + bia0.x), wn0.x, p);
            p = fmaf(clip(g0.y + bia0.y), wn0.y, p);
            p = fmaf(clip(g1.x + bia0.z), wn0.z, p);
            p = fmaf(clip(g1.y + bia0.w), wn0.w, p);
            p = fmaf(clip(g2.x + bia1.x), wn1.x, p);
            p = fmaf(clip(g2.y + bia1.y), wn1.y, p);
            p = fmaf(clip(g3.x + bia1.z), wn1.z, p);
            p = fmaf(clip(g3.y + bia1.w), wn1.w, p);
        }

        // reduce 8 lanes of the sample group (tid = grp*8 + jj, contiguous)
        p += __shfl_down(p, 1, 64);
        p += __shfl_down(p, 2, 64);
        p += __shfl_down(p, 4, 64);
        if (jj == 0) partials[c * BATCH + b] = p;   // plain store
    }
}

// Epilogue: sum 16 chunk-partials per sample, + out_b, sigmoid.
__global__ __launch_bounds__(256) void reduce_sigmoid_kernel(
    const float* __restrict__ partials,
    const float* __restrict__ out_b,
    float* __restrict__ out)
{
    const int i = blockIdx.x * 256 + threadIdx.x;
    float s = out_b[0];
    #pragma unroll
    for (int k = 0; k < NCHUNK; ++k)
        s += partials[k * BATCH + i];
    out[i] = 1.f / (1.f + expf(-s));
}

extern "C" void kernel_launch(void* const* d_in, const int* in_sizes, int n_in,
                              void* d_out, int out_size, void* d_ws, size_t ws_size,
                              hipStream_t stream) {
    const float* values   = (const float*)d_in[0];
    const int*   stm_idx  = (const int*)d_in[1];
    const int*   nstm_idx = (const int*)d_in[2];
    const float* ft_w     = (const float*)d_in[3];
    const float* ft_b     = (const float*)d_in[4];
    const float* out_w    = (const float*)d_in[5];
    const float* out_b    = (const float*)d_in[6];
    float*       out      = (float*)d_out;

    float* partials = (float*)d_ws;   // [16][16384] f32 = 1 MB, fully overwritten

    hipFuncSetAttribute((const void*)nnboard_main,
                        hipFuncAttributeMaxDynamicSharedMemorySize, LDS_BYTES);

    nnboard_main<<<NCHUNK * GROUPS, 256, LDS_BYTES, stream>>>(
        values, stm_idx, nstm_idx, ft_w, ft_b, out_w, partials);
    reduce_sigmoid_kernel<<<BATCH / 256, 256, 0, stream>>>(partials, out_b, out);
}

// Round 12
// 134.182 us; speedup vs baseline: 1.4030x; 1.4030x over previous
//
#include <hip/hip_runtime.h>
#include <hip/hip_fp16.h>
#include <math.h>

#define BATCH 16384
#define MAXF 32
#define NFEAT 768
#define FT_OUT 1024
#define CHUNK 64                      // 128-B LDS row: sample's 8xb128 sweeps all 32 banks
#define NCHUNK (FT_OUT / CHUNK)       // 16 chunks
#define GROUPS 16                     // stripes -> 256 blocks = 1/CU (96 KiB LDS)
#define CH_HALVES (NFEAT * CHUNK)     // 49152 halves = 96 KiB
#define LDS_BYTES (CH_HALVES * 2)
#define NIT (BATCH / 32 / GROUPS)     // 32 iterations per block, uniform

typedef unsigned int uint_t;

// One feature step: gather stm+nstm rows for this lane's 8 cols, packed-fma.
#define STEP(IS, IN, VF) do {                                          \
    const __half2 v2 = __float2half2_rn(VF);                           \
    const uint4 qs = *(const uint4*)(my_tab + (size_t)(IS) * CHUNK);   \
    const uint4 qn = *(const uint4*)(my_tab + (size_t)(IN) * CHUNK);   \
    accs0 = __hfma2(*(const __half2*)&qs.x, v2, accs0);                \
    accs1 = __hfma2(*(const __half2*)&qs.y, v2, accs1);                \
    accs2 = __hfma2(*(const __half2*)&qs.z, v2, accs2);                \
    accs3 = __hfma2(*(const __half2*)&qs.w, v2, accs3);                \
    accn0 = __hfma2(*(const __half2*)&qn.x, v2, accn0);                \
    accn1 = __hfma2(*(const __half2*)&qn.y, v2, accn1);                \
    accn2 = __hfma2(*(const __half2*)&qn.z, v2, accn2);                \
    accn3 = __hfma2(*(const __half2*)&qn.w, v2, accn3);                \
} while (0)

#define STEP4(CS, CN, CV) STEP((CS).x, (CN).x, (CV).x); \
                          STEP((CS).y, (CN).y, (CV).y); \
                          STEP((CS).z, (CN).z, (CV).z); \
                          STEP((CS).w, (CN).w, (CV).w)

// All 32 features of the current sample, from NAMED registers (no arrays ->
// nothing can spill to scratch; R7/R11 lesson: dynamic LDS breaks array
// register-promotion, VGPR 80 -> 32, 2.5x slowdown).
#define COMPUTE_ALL() do {                                             \
    STEP4(cs0, cn0, cv0); STEP4(cs1, cn1, cv1);                        \
    STEP4(cs2, cn2, cv2); STEP4(cs3, cn3, cv3);                        \
    STEP4(cs4, cn4, cv4); STEP4(cs5, cn5, cv5);                        \
    STEP4(cs6, cn6, cv6); STEP4(cs7, cn7, cv7);                        \
} while (0)

__global__ __launch_bounds__(256, 1) void nnboard_main(
    const float* __restrict__ values,
    const int*   __restrict__ stm_idx,
    const int*   __restrict__ nstm_idx,
    const float* __restrict__ ft_w,
    const float* __restrict__ ft_b,
    const float* __restrict__ out_w,
    float*       __restrict__ partials)   // [NCHUNK][BATCH]
{
    extern __shared__ __half s_tab[];     // [NFEAT][CHUNK], row = 128 B

    const int tid = threadIdx.x;
    const int c = blockIdx.x & (NCHUNK - 1);
    const int g = blockIdx.x >> 4;        // stripe 0..15
    const __half2 zero2 = __float2half2_rn(0.f);

    // ---- stage chunk c from fp32 ft_w (static indexing only)
    {
        const int lane8 = tid & 7;
        const int rbase = tid >> 3;       // 32 rows per sweep
        #pragma unroll
        for (int k = 0; k < NFEAT / 32; ++k) {
            const int r = k * 32 + rbase;
            const float* src = ft_w + (size_t)r * FT_OUT + c * CHUNK + lane8 * 8;
            const float4 f0 = *(const float4*)(src);
            const float4 f1 = *(const float4*)(src + 4);
            __half2 h0 = __floats2half2_rn(f0.x, f0.y);
            __half2 h1 = __floats2half2_rn(f0.z, f0.w);
            __half2 h2 = __floats2half2_rn(f1.x, f1.y);
            __half2 h3 = __floats2half2_rn(f1.z, f1.w);
            uint4 u;
            u.x = *reinterpret_cast<uint_t*>(&h0);
            u.y = *reinterpret_cast<uint_t*>(&h1);
            u.z = *reinterpret_cast<uint_t*>(&h2);
            u.w = *reinterpret_cast<uint_t*>(&h3);
            *(uint4*)(s_tab + r * CHUNK + lane8 * 8) = u;
        }
    }
    __syncthreads();

    const int grp = tid >> 3;             // 0..31 : sample slot per iteration
    const int jj  = tid & 7;              // lane within sample (owns 8 cols)
    const int col0 = c * CHUNK + jj * 8;
    const __half* my_tab = s_tab + jj * 8;

    const float4 bia0 = *(const float4*)(ft_b + col0);
    const float4 bia1 = *(const float4*)(ft_b + col0 + 4);
    const float4 ws0  = *(const float4*)(out_w + col0);
    const float4 ws1  = *(const float4*)(out_w + col0 + 4);
    const float4 wn0  = *(const float4*)(out_w + FT_OUT + col0);
    const float4 wn1  = *(const float4*)(out_w + FT_OUT + col0 + 4);

    // ---- manual 2-stage pipeline over 32 iterations (b advances by 512)
    int b = g * 32 + grp;

    const int4*   sp = (const int4*)(stm_idx + (size_t)b * MAXF);
    const int4*   np = (const int4*)(nstm_idx + (size_t)b * MAXF);
    const float4* vp = (const float4*)(values + (size_t)b * MAXF);
    int4 cs0 = sp[0], cs1 = sp[1], cs2 = sp[2], cs3 = sp[3],
         cs4 = sp[4], cs5 = sp[5], cs6 = sp[6], cs7 = sp[7];
    int4 cn0 = np[0], cn1 = np[1], cn2 = np[2], cn3 = np[3],
         cn4 = np[4], cn5 = np[5], cn6 = np[6], cn7 = np[7];
    float4 cv0 = vp[0], cv1 = vp[1], cv2 = vp[2], cv3 = vp[3],
           cv4 = vp[4], cv5 = vp[5], cv6 = vp[6], cv7 = vp[7];

    for (int i = 0; i < NIT; ++i) {
        // prefetch next iteration's idx/vals while current compute runs
        int4 ps0, ps1, ps2, ps3, ps4, ps5, ps6, ps7;
        int4 pn0, pn1, pn2, pn3, pn4, pn5, pn6, pn7;
        float4 pv0, pv1, pv2, pv3, pv4, pv5, pv6, pv7;
        if (i + 1 < NIT) {
            const int bn = b + 512;
            const int4*   sp2 = (const int4*)(stm_idx + (size_t)bn * MAXF);
            const int4*   np2 = (const int4*)(nstm_idx + (size_t)bn * MAXF);
            const float4* vp2 = (const float4*)(values + (size_t)bn * MAXF);
            ps0 = sp2[0]; ps1 = sp2[1]; ps2 = sp2[2]; ps3 = sp2[3];
            ps4 = sp2[4]; ps5 = sp2[5]; ps6 = sp2[6]; ps7 = sp2[7];
            pn0 = np2[0]; pn1 = np2[1]; pn2 = np2[2]; pn3 = np2[3];
            pn4 = np2[4]; pn5 = np2[5]; pn6 = np2[6]; pn7 = np2[7];
            pv0 = vp2[0]; pv1 = vp2[1]; pv2 = vp2[2]; pv3 = vp2[3];
            pv4 = vp2[4]; pv5 = vp2[5]; pv6 = vp2[6]; pv7 = vp2[7];
        }

        __half2 accs0 = zero2, accs1 = zero2, accs2 = zero2, accs3 = zero2;
        __half2 accn0 = zero2, accn1 = zero2, accn2 = zero2, accn3 = zero2;

        COMPUTE_ALL();

        float p = 0.f;
        {
            const float2 f0 = __half22float2(accs0);
            const float2 f1 = __half22float2(accs1);
            const float2 f2 = __half22float2(accs2);
            const float2 f3 = __half22float2(accs3);
            const float2 g0 = __half22float2(accn0);
            const float2 g1 = __half22float2(accn1);
            const float2 g2 = __half22float2(accn2);
            const float2 g3 = __half22float2(accn3);
            auto clip = [](float x) { return fminf(fmaxf(x, 0.f), 1.f); };
            p = fmaf(clip(f0.x + bia0.x), ws0.x, p);
            p = fmaf(clip(f0.y + bia0.y), ws0.y, p);
            p = fmaf(clip(f1.x + bia0.z), ws0.z, p);
            p = fmaf(clip(f1.y + bia0.w), ws0.w, p);
            p = fmaf(clip(f2.x + bia1.x), ws1.x, p);
            p = fmaf(clip(f2.y + bia1.y), ws1.y, p);
            p = fmaf(clip(f3.x + bia1.z), ws1.z, p);
            p = fmaf(clip(f3.y + bia1.w), ws1.w, p);
            p = fmaf(clip(g0.x + bia0.x), wn0.x, p);
            p = fmaf(clip(g0.y + bia0.y), wn0.y, p);
            p = fmaf(clip(g1.x + bia0.z), wn0.z, p);
            p = fmaf(clip(g1.y + bia0.w), wn0.w, p);
            p = fmaf(clip(g2.x + bia1.x), wn1.x, p);
            p = fmaf(clip(g2.y + bia1.y), wn1.y, p);
            p = fmaf(clip(g3.x + bia1.z), wn1.z, p);
            p = fmaf(clip(g3.y + bia1.w), wn1.w, p);
        }

        // reduce 8 lanes of the sample group (tid = grp*8 + jj, aligned)
        p += __shfl_down(p, 1, 64);
        p += __shfl_down(p, 2, 64);
        p += __shfl_down(p, 4, 64);
        if (jj == 0) partials[c * BATCH + b] = p;   // plain store

        // rotate pipeline
        cs0 = ps0; cs1 = ps1; cs2 = ps2; cs3 = ps3;
        cs4 = ps4; cs5 = ps5; cs6 = ps6; cs7 = ps7;
        cn0 = pn0; cn1 = pn1; cn2 = pn2; cn3 = pn3;
        cn4 = pn4; cn5 = pn5; cn6 = pn6; cn7 = pn7;
        cv0 = pv0; cv1 = pv1; cv2 = pv2; cv3 = pv3;
        cv4 = pv4; cv5 = pv5; cv6 = pv6; cv7 = pv7;
        b += 512;
    }
}

// Epilogue: sum 16 chunk-partials per sample, + out_b, sigmoid.
__global__ __launch_bounds__(256) void reduce_sigmoid_kernel(
    const float* __restrict__ partials,
    const float* __restrict__ out_b,
    float* __restrict__ out)
{
    const int i = blockIdx.x * 256 + threadIdx.x;
    float s = out_b[0];
    #pragma unroll
    for (int k = 0; k < NCHUNK; ++k)
        s += partials[k * BATCH + i];
    out[i] = 1.f / (1.f + expf(-s));
}

extern "C" void kernel_launch(void* const* d_in, const int* in_sizes, int n_in,
                              void* d_out, int out_size, void* d_ws, size_t ws_size,
                              hipStream_t stream) {
    const float* values   = (const float*)d_in[0];
    const int*   stm_idx  = (const int*)d_in[1];
    const int*   nstm_idx = (const int*)d_in[2];
    const float* ft_w     = (const float*)d_in[3];
    const float* ft_b     = (const float*)d_in[4];
    const float* out_w    = (const float*)d_in[5];
    const float* out_b    = (const float*)d_in[6];
    float*       out      = (float*)d_out;

    float* partials = (float*)d_ws;   // [16][16384] f32 = 1 MB, fully overwritten

    hipFuncSetAttribute((const void*)nnboard_main,
                        hipFuncAttributeMaxDynamicSharedMemorySize, LDS_BYTES);

    nnboard_main<<<NCHUNK * GROUPS, 256, LDS_BYTES, stream>>>(
        values, stm_idx, nstm_idx, ft_w, ft_b, out_w, partials);
    reduce_sigmoid_kernel<<<BATCH / 256, 256, 0, stream>>>(partials, out_b, out);
}